// Round 1
// baseline (44.613 us; speedup 1.0000x reference)
//
#include <hip/hip_runtime.h>
#include <math.h>

#define BB 16384
#define KK_N 32
#define DD 64
#define N_ENT 100000
#define N_REL 32

// ws layout (floats): [0, N_ENT) ent_scale ; [N_ENT, N_ENT + N_REL*DD) renormed rel table

__global__ __launch_bounds__(256) void precompute_kernel(
    const float* __restrict__ ent, const float* __restrict__ rel, float* __restrict__ ws)
{
    const int lane = threadIdx.x & 63;
    const int wave = threadIdx.x >> 6;
    const int row = blockIdx.x * 4 + wave;
    float* ent_scale = ws;
    float* rel_out = ws + N_ENT;

    if (row < N_ENT) {
        float v = ent[(size_t)row * DD + lane];
        float ss = v * v;
        #pragma unroll
        for (int m = 1; m < 64; m <<= 1) ss += __shfl_xor(ss, m, 64);
        float n = sqrtf(ss);
        float sc = (n > 1.0f) ? __builtin_amdgcn_rcpf(n) : 1.0f;
        if (lane == 0) ent_scale[row] = sc;
    } else if (row < N_ENT + N_REL) {
        int r = row - N_ENT;
        float v = rel[r * DD + lane];
        float ss = v * v;
        #pragma unroll
        for (int m = 1; m < 64; m <<= 1) ss += __shfl_xor(ss, m, 64);
        float n = sqrtf(ss);
        float sc = (n > 1.0f) ? __builtin_amdgcn_rcpf(n) : 1.0f;
        rel_out[r * DD + lane] = v * sc;
    }
}

__global__ __launch_bounds__(256) void kgcn_main(
    const float* __restrict__ user_table,
    const float* __restrict__ entity_table,
    const float* __restrict__ rel_renorm,   // ws (renormed)
    const float* __restrict__ ent_scale,    // ws
    const float* __restrict__ W,
    const float* __restrict__ bias,
    const int*   __restrict__ users,
    const int*   __restrict__ items,
    const int*   __restrict__ adj_entity,
    const int*   __restrict__ adj_relation,
    float* __restrict__ out_user,
    float* __restrict__ out_final)
{
    // W element (d,j) stored at Wlds[d*64 + (j ^ ((d&15)<<2))]  -> conflict-lite b128 row reads
    __shared__ __align__(16) float Wlds[64 * 64];
    __shared__ __align__(16) float RelLds[N_REL * DD];
    __shared__ __align__(16) float Vec[4][64];

    const int tid  = threadIdx.x;
    const int lane = tid & 63;
    const int wave = tid >> 6;

    // ---- stage W (swizzled) ----
    #pragma unroll
    for (int it = 0; it < 4; ++it) {
        int i = tid + it * 256;                 // float4 index, 1024 total
        float4 w4 = reinterpret_cast<const float4*>(W)[i];
        int d = (i * 4) >> 6;
        int j = (i * 4) & 63;
        int pos = j ^ ((d & 15) << 2);
        *reinterpret_cast<float4*>(&Wlds[d * 64 + pos]) = w4;
    }
    // ---- stage renormed relation table (swizzled) ----
    #pragma unroll
    for (int it = 0; it < 2; ++it) {
        int i = tid + it * 256;                 // float4 index, 512 total
        float4 r4 = reinterpret_cast<const float4*>(rel_renorm)[i];
        int r = (i * 4) >> 6;
        int j = (i * 4) & 63;
        int pos = j ^ ((r & 15) << 2);
        *reinterpret_cast<float4*>(&RelLds[r * 64 + pos]) = r4;
    }
    __syncthreads();

    const int b = blockIdx.x * 4 + wave;
    const int uid = users[b];
    const int iid = items[b];

    // ---- user embedding renorm ----
    float u = user_table[(size_t)uid * DD + lane];
    float ss = u * u;
    #pragma unroll
    for (int m = 1; m < 64; m <<= 1) ss += __shfl_xor(ss, m, 64);
    float n = sqrtf(ss);
    float usc = (n > 1.0f) ? __builtin_amdgcn_rcpf(n) : 1.0f;
    u *= usc;
    out_user[(size_t)b * DD + lane] = u;
    Vec[wave][lane] = u;

    // ---- adjacency row: lanes 0..31 -> entity ids, lanes 32..63 -> relation ids ----
    const int kk = lane & 31;
    const int* adj_base = (lane < 32) ? adj_entity : adj_relation;
    const int adjv = adj_base[(size_t)iid * KK_N + kk];
    // gather entity scale (meaningful for lanes < 32; harmless valid read otherwise)
    const float sg = ent_scale[adjv];

    // ---- scores: each lane computes score for neighbor kk ----
    const int rid = __shfl(adjv, 32 + kk, 64);
    const int srel = (rid & 15) << 2;
    const float* relrow = &RelLds[rid * 64];
    float score = 0.0f;
    #pragma unroll
    for (int d0 = 0; d0 < 64; d0 += 4) {
        float4 rv = *reinterpret_cast<const float4*>(&relrow[d0 ^ srel]); // = rel[rid][d0..d0+3]
        float4 uv = *reinterpret_cast<const float4*>(&Vec[wave][d0]);     // broadcast
        score += uv.x * rv.x + uv.y * rv.y + uv.z * rv.z + uv.w * rv.w;
    }

    // ---- softmax over 32 neighbors (butterfly within each 32-lane half) ----
    float mx = score;
    #pragma unroll
    for (int m = 1; m < 32; m <<= 1) mx = fmaxf(mx, __shfl_xor(mx, m, 64));
    float e = __expf(score - mx);
    float sum = e;
    #pragma unroll
    for (int m = 1; m < 32; m <<= 1) sum += __shfl_xor(sum, m, 64);
    const float attn = e * __builtin_amdgcn_rcpf(sum);
    const float c = attn * sg;   // attn_k * ent_scale[eid_k] on lane k (<32)

    // ---- item embedding ----
    const float isc = ent_scale[iid];
    const float item = entity_table[(size_t)iid * DD + lane] * isc;

    // ---- attention-weighted neighbor aggregation (coalesced 256B gathers) ----
    float acc = 0.0f;
    #pragma unroll
    for (int k = 0; k < KK_N; ++k) {
        int   eid = __shfl(adjv, k, 64);
        float ck  = __shfl(c,    k, 64);
        acc = fmaf(ck, entity_table[(size_t)eid * DD + lane], acc);
    }

    const float tmp = item + acc;
    Vec[wave][lane] = tmp;   // reuse per-wave vector slot (same-wave LDS ordering)

    // ---- out = relu(tmp @ W^T + b) ; lane = output dim d ----
    const int twz = (lane & 15) << 2;
    const float* wrow = &Wlds[lane * 64];
    float o = bias[lane];
    #pragma unroll
    for (int j0 = 0; j0 < 64; j0 += 4) {
        float4 wv = *reinterpret_cast<const float4*>(&wrow[j0 ^ twz]);  // = W[lane][j0..j0+3]
        float4 tv = *reinterpret_cast<const float4*>(&Vec[wave][j0]);   // broadcast
        o += tv.x * wv.x + tv.y * wv.y + tv.z * wv.z + tv.w * wv.w;
    }
    o = fmaxf(o, 0.0f);
    out_final[(size_t)b * DD + lane] = o;
}

extern "C" void kernel_launch(void* const* d_in, const int* in_sizes, int n_in,
                              void* d_out, int out_size, void* d_ws, size_t ws_size,
                              hipStream_t stream)
{
    const float* user_table     = (const float*)d_in[0];
    const float* entity_table   = (const float*)d_in[1];
    const float* relation_table = (const float*)d_in[2];
    const float* W              = (const float*)d_in[3];
    const float* bias           = (const float*)d_in[4];
    const int*   users          = (const int*)d_in[5];
    const int*   items          = (const int*)d_in[6];
    const int*   adj_entity     = (const int*)d_in[7];
    const int*   adj_relation   = (const int*)d_in[8];

    float* ws        = (float*)d_ws;
    float* out_user  = (float*)d_out;
    float* out_final = (float*)d_out + (size_t)BB * DD;

    const int pre_rows = N_ENT + N_REL;
    precompute_kernel<<<(pre_rows + 3) / 4, 256, 0, stream>>>(entity_table, relation_table, ws);
    kgcn_main<<<BB / 4, 256, 0, stream>>>(user_table, entity_table, ws + N_ENT, ws,
                                          W, bias, users, items, adj_entity, adj_relation,
                                          out_user, out_final);
}

// Round 2
// 39.336 us; speedup vs baseline: 1.1342x; 1.1342x over previous
//
#include <hip/hip_runtime.h>
#include <math.h>

#define BB 16384
#define KK_N 32
#define DD 64
#define N_ENT 100000
#define N_REL 32
#define NBLK 1024
#define BPW 4   // batch elements per wave: NBLK*4*BPW == BB

__device__ __forceinline__ float dot4(float4 a, float4 b) {
    return a.x * b.x + a.y * b.y + a.z * b.z + a.w * b.w;
}

__global__ __launch_bounds__(256) void kgcn_fused(
    const float* __restrict__ user_table,
    const float* __restrict__ entity_table,
    const float* __restrict__ relation_table,
    const float* __restrict__ W,
    const float* __restrict__ bias,
    const int*   __restrict__ users,
    const int*   __restrict__ items,
    const int*   __restrict__ adj_entity,
    const int*   __restrict__ adj_relation,
    float* __restrict__ out_user,
    float* __restrict__ out_final)
{
    // W element (d,j) at Wlds[d*64 + (j ^ ((d&15)<<2))]
    // Rel element (r,j) at RelLds[r*64 + (j ^ ((r&15)<<2))], pre-renormed
    __shared__ __align__(16) float Wlds[64 * 64];
    __shared__ __align__(16) float RelLds[N_REL * DD];
    __shared__ __align__(16) float Vec[4][64];

    const int tid  = threadIdx.x;
    const int lane = tid & 63;
    const int wave = tid >> 6;
    const int grp  = lane >> 4;   // 16-lane group within wave
    const int gl   = lane & 15;   // lane within group

    // ---- stage W (swizzled) ----
    #pragma unroll
    for (int it = 0; it < 4; ++it) {
        int i = tid + it * 256;                       // float4 index
        float4 w4 = reinterpret_cast<const float4*>(W)[i];
        int d = i >> 4;
        int j = (i & 15) * 4;
        *reinterpret_cast<float4*>(&Wlds[d * 64 + (j ^ ((d & 15) << 2))]) = w4;
    }
    // ---- stage relation table, renorm inline (4 rows per wave-iter) ----
    #pragma unroll
    for (int it = 0; it < 2; ++it) {
        int r = wave * 8 + it * 4 + grp;
        float4 v = reinterpret_cast<const float4*>(relation_table)[r * 16 + gl];
        float ss = dot4(v, v);
        #pragma unroll
        for (int m = 1; m < 16; m <<= 1) ss += __shfl_xor(ss, m, 64);
        float sc = fminf(1.0f, __builtin_amdgcn_rsqf(ss));
        v.x *= sc; v.y *= sc; v.z *= sc; v.w *= sc;
        *reinterpret_cast<float4*>(&RelLds[r * 64 + ((gl * 4) ^ ((r & 15) << 2))]) = v;
    }
    __syncthreads();

    const float bv = bias[lane];
    const float* wrow = &Wlds[lane * 64];
    const int twz = (lane & 15) << 2;
    const int kk = lane & 31;
    const int b0 = blockIdx.x * (4 * BPW) + wave * BPW;

    for (int ib = 0; ib < BPW; ++ib) {
        const int b = b0 + ib;
        const int uid = __builtin_amdgcn_readfirstlane(users[b]);
        const int iid = __builtin_amdgcn_readfirstlane(items[b]);

        // ---- adjacency: lanes 0..31 entity ids, lanes 32..63 relation ids ----
        const int* abase = (lane < 32) ? adj_entity : adj_relation;
        const int adjv = abase[(size_t)iid * KK_N + kk];

        // ---- user embedding renorm (16-lane float4 groups; all groups identical) ----
        float4 uv = *reinterpret_cast<const float4*>(&user_table[(size_t)uid * DD + gl * 4]);
        float ssu = dot4(uv, uv);
        #pragma unroll
        for (int m = 1; m < 16; m <<= 1) ssu += __shfl_xor(ssu, m, 64);
        float usc = fminf(1.0f, __builtin_amdgcn_rsqf(ssu));
        uv.x *= usc; uv.y *= usc; uv.z *= usc; uv.w *= usc;
        if (lane < 16) {
            *reinterpret_cast<float4*>(&out_user[(size_t)b * DD + gl * 4]) = uv;
            *reinterpret_cast<float4*>(&Vec[wave][gl * 4]) = uv;
        }

        // ---- scores: lane kk (both halves) scores neighbor kk ----
        const int rid = __shfl(adjv, 32 + kk, 64);
        const int srel = (rid & 15) << 2;
        const float* relrow = &RelLds[rid * 64];
        float score = 0.0f;
        #pragma unroll
        for (int d0 = 0; d0 < 64; d0 += 4) {
            float4 rv = *reinterpret_cast<const float4*>(&relrow[d0 ^ srel]);
            float4 tv = *reinterpret_cast<const float4*>(&Vec[wave][d0]);
            score += dot4(tv, rv);
        }
        // softmax over 32 neighbors (butterfly within each half)
        float mx = score;
        #pragma unroll
        for (int m = 1; m < 32; m <<= 1) mx = fmaxf(mx, __shfl_xor(mx, m, 64));
        float e = __expf(score - mx);
        float sum = e;
        #pragma unroll
        for (int m = 1; m < 32; m <<= 1) sum += __shfl_xor(sum, m, 64);
        const float attn = e * __builtin_amdgcn_rcpf(sum);

        // ---- gather + inline-renorm + aggregate: 4 rows per load step ----
        int   eid[8];
        float cc[8];
        #pragma unroll
        for (int k0 = 0; k0 < 8; ++k0) {
            int k = k0 * 4 + grp;
            eid[k0] = __shfl(adjv, k, 64);
            cc[k0]  = __shfl(attn, k, 64);
        }
        float4 v[8];
        #pragma unroll
        for (int k0 = 0; k0 < 8; ++k0)
            v[k0] = *reinterpret_cast<const float4*>(&entity_table[(size_t)eid[k0] * DD + gl * 4]);

        float4 acc = make_float4(0.f, 0.f, 0.f, 0.f);
        #pragma unroll
        for (int k0 = 0; k0 < 8; ++k0) {
            float ss = dot4(v[k0], v[k0]);
            #pragma unroll
            for (int m = 1; m < 16; m <<= 1) ss += __shfl_xor(ss, m, 64);
            float sc = fminf(1.0f, __builtin_amdgcn_rsqf(ss));
            float ck = cc[k0] * sc;
            acc.x = fmaf(ck, v[k0].x, acc.x);
            acc.y = fmaf(ck, v[k0].y, acc.y);
            acc.z = fmaf(ck, v[k0].z, acc.z);
            acc.w = fmaf(ck, v[k0].w, acc.w);
        }
        // cross-group reduce (groups held different neighbors)
        #pragma unroll
        for (int m = 16; m < 64; m <<= 1) {
            acc.x += __shfl_xor(acc.x, m, 64);
            acc.y += __shfl_xor(acc.y, m, 64);
            acc.z += __shfl_xor(acc.z, m, 64);
            acc.w += __shfl_xor(acc.w, m, 64);
        }

        // ---- item embedding renorm + add ----
        float4 iv = *reinterpret_cast<const float4*>(&entity_table[(size_t)iid * DD + gl * 4]);
        float ssi = dot4(iv, iv);
        #pragma unroll
        for (int m = 1; m < 16; m <<= 1) ssi += __shfl_xor(ssi, m, 64);
        float isc = fminf(1.0f, __builtin_amdgcn_rsqf(ssi));
        float4 tmp;
        tmp.x = fmaf(isc, iv.x, acc.x);
        tmp.y = fmaf(isc, iv.y, acc.y);
        tmp.z = fmaf(isc, iv.z, acc.z);
        tmp.w = fmaf(isc, iv.w, acc.w);
        if (lane < 16)
            *reinterpret_cast<float4*>(&Vec[wave][gl * 4]) = tmp;

        // ---- out = relu(tmp @ W^T + b); lane = output dim ----
        float o = bv;
        #pragma unroll
        for (int j0 = 0; j0 < 64; j0 += 4) {
            float4 wv = *reinterpret_cast<const float4*>(&wrow[j0 ^ twz]);
            float4 tv = *reinterpret_cast<const float4*>(&Vec[wave][j0]);
            o += dot4(tv, wv);
        }
        out_final[(size_t)b * DD + lane] = fmaxf(o, 0.0f);
    }
}

extern "C" void kernel_launch(void* const* d_in, const int* in_sizes, int n_in,
                              void* d_out, int out_size, void* d_ws, size_t ws_size,
                              hipStream_t stream)
{
    const float* user_table     = (const float*)d_in[0];
    const float* entity_table   = (const float*)d_in[1];
    const float* relation_table = (const float*)d_in[2];
    const float* W              = (const float*)d_in[3];
    const float* bias           = (const float*)d_in[4];
    const int*   users          = (const int*)d_in[5];
    const int*   items          = (const int*)d_in[6];
    const int*   adj_entity     = (const int*)d_in[7];
    const int*   adj_relation   = (const int*)d_in[8];

    float* out_user  = (float*)d_out;
    float* out_final = (float*)d_out + (size_t)BB * DD;

    kgcn_fused<<<NBLK, 256, 0, stream>>>(user_table, entity_table, relation_table,
                                         W, bias, users, items, adj_entity, adj_relation,
                                         out_user, out_final);
}

// Round 3
// 31.382 us; speedup vs baseline: 1.4216x; 1.2535x over previous
//
#include <hip/hip_runtime.h>
#include <math.h>

#define BB 16384
#define KK_N 32
#define DD 64
#define N_ENT 100000
#define N_REL 32
#define NBLK 4096   // 4 waves/block, 1 batch element per wave

__device__ __forceinline__ float dot4(float4 a, float4 b) {
    return a.x * b.x + a.y * b.y + a.z * b.z + a.w * b.w;
}

__global__ __launch_bounds__(256) void kgcn_fused(
    const float* __restrict__ user_table,
    const float* __restrict__ entity_table,
    const float* __restrict__ relation_table,
    const float* __restrict__ W,
    const float* __restrict__ bias,
    const int*   __restrict__ users,
    const int*   __restrict__ items,
    const int*   __restrict__ adj_entity,
    const int*   __restrict__ adj_relation,
    float* __restrict__ out_user,
    float* __restrict__ out_final)
{
    // W element (d,j) at Wlds[d*64 + (j ^ ((d&15)<<2))]
    // Rel element (r,j) at RelLds[r*64 + (j ^ ((r&15)<<2))], pre-renormed
    __shared__ __align__(16) float Wlds[64 * 64];
    __shared__ __align__(16) float RelLds[N_REL * DD];
    __shared__ __align__(16) float Vec[4][64];

    const int tid  = threadIdx.x;
    const int lane = tid & 63;
    const int wave = tid >> 6;
    const int grp  = lane >> 4;   // 16-lane group within wave
    const int gl   = lane & 15;   // lane within group

    const int b = blockIdx.x * 4 + wave;
    const int uid = __builtin_amdgcn_readfirstlane(users[b]);
    const int iid = __builtin_amdgcn_readfirstlane(items[b]);

    // ---- independent loads issued early (overlap with LDS staging) ----
    const int kk = lane & 31;
    const int* abase = (lane < 32) ? adj_entity : adj_relation;
    const int adjv = abase[(size_t)iid * KK_N + kk];          // ent ids | rel ids
    float4 uv = *reinterpret_cast<const float4*>(&user_table[(size_t)uid * DD + gl * 4]);
    float4 iv = *reinterpret_cast<const float4*>(&entity_table[(size_t)iid * DD + gl * 4]);

    // ---- stage W (swizzled) ----
    #pragma unroll
    for (int it = 0; it < 4; ++it) {
        int i = tid + it * 256;                       // float4 index
        float4 w4 = reinterpret_cast<const float4*>(W)[i];
        int d = i >> 4;
        int j = (i & 15) * 4;
        *reinterpret_cast<float4*>(&Wlds[d * 64 + (j ^ ((d & 15) << 2))]) = w4;
    }
    // ---- stage relation table, renorm inline (4 rows per wave-iter) ----
    #pragma unroll
    for (int it = 0; it < 2; ++it) {
        int r = wave * 8 + it * 4 + grp;
        float4 v = reinterpret_cast<const float4*>(relation_table)[r * 16 + gl];
        float ss = dot4(v, v);
        #pragma unroll
        for (int m = 1; m < 16; m <<= 1) ss += __shfl_xor(ss, m, 64);
        float sc = fminf(1.0f, __builtin_amdgcn_rsqf(ss));
        v.x *= sc; v.y *= sc; v.z *= sc; v.w *= sc;
        *reinterpret_cast<float4*>(&RelLds[r * 64 + ((gl * 4) ^ ((r & 15) << 2))]) = v;
    }

    // ---- user embedding renorm (independent of LDS) ----
    float ssu = dot4(uv, uv);
    #pragma unroll
    for (int m = 1; m < 16; m <<= 1) ssu += __shfl_xor(ssu, m, 64);
    float usc = fminf(1.0f, __builtin_amdgcn_rsqf(ssu));
    uv.x *= usc; uv.y *= usc; uv.z *= usc; uv.w *= usc;
    if (lane < 16)
        *reinterpret_cast<float4*>(&out_user[(size_t)b * DD + gl * 4]) = uv;

    // ---- start the neighbor gathers as early as possible ----
    int   eid[8];
    #pragma unroll
    for (int k0 = 0; k0 < 8; ++k0)
        eid[k0] = __shfl(adjv, k0 * 4 + grp, 64);
    float4 v[8];
    #pragma unroll
    for (int k0 = 0; k0 < 8; ++k0)
        v[k0] = *reinterpret_cast<const float4*>(&entity_table[(size_t)eid[k0] * DD + gl * 4]);

    __syncthreads();
    if (lane < 16)
        *reinterpret_cast<float4*>(&Vec[wave][gl * 4]) = uv;

    // ---- scores: lane L scores neighbor L&31 over half the dims; halves combine ----
    const int rid = __shfl(adjv, 32 + kk, 64);
    const int srel = (rid & 15) << 2;
    const float* relrow = &RelLds[rid * 64];
    const int dbase = (lane >> 5) * 32;
    float score = 0.0f;
    #pragma unroll
    for (int d0 = 0; d0 < 32; d0 += 4) {
        int d = dbase + d0;
        float4 rv = *reinterpret_cast<const float4*>(&relrow[d ^ srel]);
        float4 tv = *reinterpret_cast<const float4*>(&Vec[wave][d]);
        score += dot4(tv, rv);
    }
    score += __shfl_xor(score, 32, 64);   // combine d-halves; both halves now full

    // softmax over 32 neighbors (butterfly within each half)
    float mx = score;
    #pragma unroll
    for (int m = 1; m < 32; m <<= 1) mx = fmaxf(mx, __shfl_xor(mx, m, 64));
    float e = __expf(score - mx);
    float sum = e;
    #pragma unroll
    for (int m = 1; m < 32; m <<= 1) sum += __shfl_xor(sum, m, 64);
    const float attn = e * __builtin_amdgcn_rcpf(sum);

    // ---- inline-renorm + aggregate the gathered rows ----
    float cc[8];
    #pragma unroll
    for (int k0 = 0; k0 < 8; ++k0)
        cc[k0] = __shfl(attn, k0 * 4 + grp, 64);

    float4 acc = make_float4(0.f, 0.f, 0.f, 0.f);
    #pragma unroll
    for (int k0 = 0; k0 < 8; ++k0) {
        float ss = dot4(v[k0], v[k0]);
        #pragma unroll
        for (int m = 1; m < 16; m <<= 1) ss += __shfl_xor(ss, m, 64);
        float sc = fminf(1.0f, __builtin_amdgcn_rsqf(ss));
        float ck = cc[k0] * sc;
        acc.x = fmaf(ck, v[k0].x, acc.x);
        acc.y = fmaf(ck, v[k0].y, acc.y);
        acc.z = fmaf(ck, v[k0].z, acc.z);
        acc.w = fmaf(ck, v[k0].w, acc.w);
    }
    // cross-group reduce (groups held different neighbors)
    #pragma unroll
    for (int m = 16; m < 64; m <<= 1) {
        acc.x += __shfl_xor(acc.x, m, 64);
        acc.y += __shfl_xor(acc.y, m, 64);
        acc.z += __shfl_xor(acc.z, m, 64);
        acc.w += __shfl_xor(acc.w, m, 64);
    }

    // ---- item embedding renorm + add ----
    float ssi = dot4(iv, iv);
    #pragma unroll
    for (int m = 1; m < 16; m <<= 1) ssi += __shfl_xor(ssi, m, 64);
    float isc = fminf(1.0f, __builtin_amdgcn_rsqf(ssi));
    float4 tmp;
    tmp.x = fmaf(isc, iv.x, acc.x);
    tmp.y = fmaf(isc, iv.y, acc.y);
    tmp.z = fmaf(isc, iv.z, acc.z);
    tmp.w = fmaf(isc, iv.w, acc.w);
    if (lane < 16)
        *reinterpret_cast<float4*>(&Vec[wave][gl * 4]) = tmp;

    // ---- out = relu(tmp @ W^T + b); lane = output dim ----
    const float bv = bias[lane];
    const float* wrow = &Wlds[lane * 64];
    const int twz = (lane & 15) << 2;
    float o = bv;
    #pragma unroll
    for (int j0 = 0; j0 < 64; j0 += 4) {
        float4 wv = *reinterpret_cast<const float4*>(&wrow[j0 ^ twz]);
        float4 tv = *reinterpret_cast<const float4*>(&Vec[wave][j0]);
        o += dot4(tv, wv);
    }
    out_final[(size_t)b * DD + lane] = fmaxf(o, 0.0f);
}

extern "C" void kernel_launch(void* const* d_in, const int* in_sizes, int n_in,
                              void* d_out, int out_size, void* d_ws, size_t ws_size,
                              hipStream_t stream)
{
    const float* user_table     = (const float*)d_in[0];
    const float* entity_table   = (const float*)d_in[1];
    const float* relation_table = (const float*)d_in[2];
    const float* W              = (const float*)d_in[3];
    const float* bias           = (const float*)d_in[4];
    const int*   users          = (const int*)d_in[5];
    const int*   items          = (const int*)d_in[6];
    const int*   adj_entity     = (const int*)d_in[7];
    const int*   adj_relation   = (const int*)d_in[8];

    float* out_user  = (float*)d_out;
    float* out_final = (float*)d_out + (size_t)BB * DD;

    kgcn_fused<<<NBLK, 256, 0, stream>>>(user_table, entity_table, relation_table,
                                         W, bias, users, items, adj_entity, adj_relation,
                                         out_user, out_final);
}